// Round 7
// baseline (703.309 us; speedup 1.0000x reference)
//
#include <hip/hip_runtime.h>
#include <hip/hip_cooperative_groups.h>
#include <math.h>

namespace cg = cooperative_groups;

#define HALO 10
#define TS 32
#define IN 42      // TS + HALO rows staged
#define NP 22      // float2 pairs staged per row (44 cols)
#define XSTR 46    // LDS row stride (words) for Xs/Ys: even (b64 ok), 2-way bank aliasing only
#define HSTR 46    // LDS row stride (words) for Hs (transposed)
#define NBIN 256   // atomic spreading: one 64B cache line (16 floats) per bin per level

typedef float f2 __attribute__((ext_vector_type(2)));

struct GaussW { float g[11]; };

__device__ void process_tile(
    const float* __restrict__ X, const float* __restrict__ Y,
    int H, int l2x, const GaussW& gw, float* __restrict__ Plevel, int last_level,
    float* __restrict__ Xpool, float* __restrict__ Ypool, int t)
{
    __shared__ float Xs[IN][XSTR];
    __shared__ float Ys[IN][XSTR];
    __shared__ float Hs[4][TS][HSTR];
    __shared__ float red[4];

    const int W = H;
    const int Hout = H - HALO;

    const int tid = threadIdx.x;
    const int ntx   = 1 << l2x;
    const int bc  = t >> (2 * l2x);            // b*3 + c
    const int rem = t & (ntx * ntx - 1);
    const int by  = rem >> l2x;
    const int bx  = rem & (ntx - 1);
    const int b   = bc / 3;
    const int r0  = by * TS;
    const int c0  = bx * TS;
    const size_t base = (size_t)bc * H * W;

    // ---- Phase 1: coalesced staging of raw tiles ----
    for (int idx = tid; idx < IN * NP; idx += 256) {
        int rr = idx / NP, pp = idx - rr * NP;
        int gr = r0 + rr, gc = c0 + 2 * pp;
        float2 xv = make_float2(0.f, 0.f), yv = make_float2(0.f, 0.f);
        if (gr < H && gc < W) {
            const float* xp = X + base + (size_t)gr * W + gc;
            const float* yp = Y + base + (size_t)gr * W + gc;
            xv = *(const float2*)xp;
            yv = *(const float2*)yp;
        }
        *(float2*)&Xs[rr][2 * pp] = xv;
        *(float2*)&Ys[rr][2 * pp] = yv;
    }
    __syncthreads();

    // ---- Phase 2 (waves 0-2): horizontal 11-tap blur of {x, y, (x+y)^2, (x-y)^2} ----
    if (tid < 168) {
        const int rr  = tid >> 2;
        const int seg = tid & 3;
        const int ccb = seg * 8;

        float x[20], y[20];
        #pragma unroll
        for (int u = 0; u < 10; ++u) {
            *(f2*)&x[2 * u] = *(const f2*)&Xs[rr][ccb + 2 * u];
            *(f2*)&y[2 * u] = *(const f2*)&Ys[rr][ccb + 2 * u];
        }

        #pragma unroll
        for (int p = 0; p < 4; ++p) {
            f2 ax = {0.f, 0.f}, ay = {0.f, 0.f};
            #pragma unroll
            for (int k = 0; k < 11; ++k) {
                f2 vx = { x[2 * p + k], x[2 * p + k + 1] };
                f2 vy = { y[2 * p + k], y[2 * p + k + 1] };
                ax += vx * gw.g[k];
                ay += vy * gw.g[k];
            }
            Hs[0][ccb + 2 * p    ][rr] = ax.x;
            Hs[0][ccb + 2 * p + 1][rr] = ax.y;
            Hs[1][ccb + 2 * p    ][rr] = ay.x;
            Hs[1][ccb + 2 * p + 1][rr] = ay.y;
        }
        #pragma unroll
        for (int i = 0; i < 9; ++i) {
            f2 xv = *(f2*)&x[2 * i];
            f2 yv = *(f2*)&y[2 * i];
            f2 a = xv + yv;
            f2 d = xv - yv;
            *(f2*)&x[2 * i] = a * a;
            *(f2*)&y[2 * i] = d * d;
        }
        #pragma unroll
        for (int p = 0; p < 4; ++p) {
            f2 as = {0.f, 0.f}, ad = {0.f, 0.f};
            #pragma unroll
            for (int k = 0; k < 11; ++k) {
                f2 vs = { x[2 * p + k], x[2 * p + k + 1] };
                f2 vd = { y[2 * p + k], y[2 * p + k + 1] };
                as += vs * gw.g[k];
                ad += vd * gw.g[k];
            }
            Hs[2][ccb + 2 * p    ][rr] = as.x;
            Hs[2][ccb + 2 * p + 1][rr] = as.y;
            Hs[3][ccb + 2 * p    ][rr] = ad.x;
            Hs[3][ccb + 2 * p + 1][rr] = ad.y;
        }
    } else if (tid >= 192 && !last_level) {
        // ---- Phase 2 (wave 3): 2x2 avg-pool straight from the LDS tile ----
        const int tt = tid - 192;
        const int Wp = W >> 1;
        #pragma unroll
        for (int q = 0; q < 4; ++q) {
            int cell = q * 64 + tt;
            int pr = cell >> 4, pc = cell & 15;
            float2 xa = *(const float2*)&Xs[2 * pr][2 * pc];
            float2 xb = *(const float2*)&Xs[2 * pr + 1][2 * pc];
            float2 ya = *(const float2*)&Ys[2 * pr][2 * pc];
            float2 yb = *(const float2*)&Ys[2 * pr + 1][2 * pc];
            size_t o = (size_t)bc * (H >> 1) * Wp + (size_t)(r0 / 2 + pr) * Wp + (c0 / 2 + pc);
            Xpool[o] = 0.25f * (xa.x + xa.y + xb.x + xb.y);
            Ypool[o] = 0.25f * (ya.x + ya.y + yb.x + yb.y);
        }
    }
    __syncthreads();

    // ---- Phase 3: vertical 11-tap blur (contiguous b64 reads, packed FMA) + SSIM ----
    const int tx = tid & 31;
    const int ty = tid >> 5;
    const int rb = ty * 4;

    f2 m1[2], m2[2], S[2], D[2];
    #define VPASS(Q, OUT)                                                        \
    {                                                                            \
        float win[14];                                                           \
        _Pragma("unroll")                                                        \
        for (int i = 0; i < 7; ++i)                                              \
            *(f2*)&win[2 * i] = *(const f2*)&Hs[Q][tx][rb + 2 * i];              \
        _Pragma("unroll")                                                        \
        for (int h = 0; h < 2; ++h) {                                            \
            f2 acc = {0.f, 0.f};                                                 \
            _Pragma("unroll")                                                    \
            for (int k = 0; k < 11; ++k) {                                       \
                f2 v = { win[2 * h + k], win[2 * h + k + 1] };                   \
                acc += v * gw.g[k];                                              \
            }                                                                    \
            OUT[h] = acc;                                                        \
        }                                                                        \
    }
    VPASS(0, m1) VPASS(1, m2) VPASS(2, S) VPASS(3, D)
    #undef VPASS

    const float C1 = 1e-4f, C2 = 9e-4f;
    float acc_s = 0.f;
    #pragma unroll
    for (int o = 0; o < 4; ++o) {
        float u1 = m1[o >> 1][o & 1], u2 = m2[o >> 1][o & 1];
        float Sv = S[o >> 1][o & 1],  Dv = D[o >> 1][o & 1];
        float u1s = u1 * u1, u2s = u2 * u2, u12 = u1 * u2;
        float ssum = 0.5f  * (Sv + Dv);
        float sxy  = 0.25f * (Sv - Dv);
        float vsum = ssum - u1s - u2s;
        float v12  = sxy - u12;
        float A2   = fmaxf(2.f * v12 + C2, 0.f);
        float B1   = u1s + u2s + C1;
        float B2   = vsum + C2;
        float inv  = __builtin_amdgcn_rcpf(B1 * B2);
        float val;
        if (!last_level) {
            val = A2 * B1 * inv;
        } else {
            float A1 = 2.f * u12 + C1;
            val = A1 * A2 * inv;
        }
        bool valid = (r0 + rb + o < Hout) && (c0 + tx < Hout);
        acc_s += valid ? val : 0.f;
    }

    // ---- Phase 4: block reduction + one atomic into a bin-spread line ----
    #pragma unroll
    for (int off = 32; off; off >>= 1) acc_s += __shfl_down(acc_s, off);
    if ((tid & 63) == 0) red[tid >> 6] = acc_s;
    __syncthreads();
    if (tid == 0) {
        int bin = t & (NBIN - 1);
        atomicAdd(&Plevel[bin * 16 + b], red[0] + red[1] + red[2] + red[3]);
    }
    __syncthreads();   // red[] reused next tile
}

__global__ __launch_bounds__(256, 4) void msssim_mega(
    const float* __restrict__ X0, const float* __restrict__ Y0,
    float* __restrict__ P,
    float* __restrict__ X1, float* __restrict__ Y1,
    float* __restrict__ X2, float* __restrict__ Y2,
    float* __restrict__ X3, float* __restrict__ Y3,
    GaussW gw, float* __restrict__ out)
{
    cg::grid_group grid = cg::this_grid();
    const int tid = threadIdx.x;

    // Zero partial sums, then barrier before any atomics
    {
        int idx = blockIdx.x * 256 + tid;
        if (idx < 4 * NBIN * 16) P[idx] = 0.f;
    }
    __threadfence();
    grid.sync();

    const float* Xl[4] = {X0, X1, X2, X3};
    const float* Yl[4] = {Y0, Y1, Y2, Y3};
    float* Xp[4] = {X1, X2, X3, nullptr};
    float* Yp[4] = {Y1, Y2, Y3, nullptr};
    const int Hl[4]     = {512, 256, 128, 64};
    const int l2xl[4]   = {4, 3, 2, 1};
    const int ntile[4]  = {12288, 3072, 768, 192};

    for (int l = 0; l < 4; ++l) {
        for (int t = blockIdx.x; t < ntile[l]; t += gridDim.x)
            process_tile(Xl[l], Yl[l], Hl[l], l2xl[l], gw, P + l * NBIN * 16,
                         l == 3, Xp[l], Yp[l], t);
        __threadfence();
        grid.sync();
    }

    // ---- Finalize (block 0) ----
    if (blockIdx.x == 0) {
        __shared__ float fred[64][4];
        const int pair = tid >> 2;     // l*16 + b
        const int chnk = tid & 3;
        const int l = pair >> 4, b = pair & 15;
        float s = 0.f;
        #pragma unroll 4
        for (int j = 0; j < 64; ++j)
            s += P[((l * NBIN) + (chnk * 64) + j) * 16 + b];
        fred[pair][chnk] = s;
        __syncthreads();
        if (tid < 16) {
            const int bb = tid;
            const float wraw[4] = {0.0448f, 0.2856f, 0.3001f, 0.2363f};
            float wsum = wraw[0] + wraw[1] + wraw[2] + wraw[3];
            float ms = 1.f;
            for (int ll = 0; ll < 4; ++ll) {
                int Hh = 512 >> ll;
                int Ho = Hh - HALO;
                float cnt = 3.f * (float)Ho * (float)Ho;
                float val = (fred[ll * 16 + bb][0] + fred[ll * 16 + bb][1] +
                             fred[ll * 16 + bb][2] + fred[ll * 16 + bb][3]) / cnt;
                val = fmaxf(val, 1e-8f);
                ms *= powf(val, wraw[ll] / wsum);
            }
            out[bb] = 1.f - ms;
        }
    }
}

extern "C" void kernel_launch(void* const* d_in, const int* in_sizes, int n_in,
                              void* d_out, int out_size, void* d_ws, size_t ws_size,
                              hipStream_t stream)
{
    const float* X0 = (const float*)d_in[0];
    const float* Y0 = (const float*)d_in[1];
    float* out = (float*)d_out;
    float* ws  = (float*)d_ws;

    const size_t PSZ = (size_t)4 * NBIN * 16;
    float* P  = ws;
    float* X1 = ws + PSZ;
    float* Y1 = X1 + (size_t)16 * 3 * 256 * 256;
    float* X2 = Y1 + (size_t)16 * 3 * 256 * 256;
    float* Y2 = X2 + (size_t)16 * 3 * 128 * 128;
    float* X3 = Y2 + (size_t)16 * 3 * 128 * 128;
    float* Y3 = X3 + (size_t)16 * 3 * 64 * 64;

    GaussW gw;
    {
        float s = 0.f;
        for (int i = 0; i < 11; ++i) {
            float d = (float)(i - 5);
            gw.g[i] = expf(-d * d / (2.f * 1.5f * 1.5f));
            s += gw.g[i];
        }
        for (int i = 0; i < 11; ++i) gw.g[i] /= s;
    }

    // Co-resident grid: blocks/CU from the occupancy API (LDS-bound, expect 4), x 256 CUs
    int maxB = 0;
    hipOccupancyMaxActiveBlocksPerMultiprocessor(&maxB, msssim_mega, 256, 0);
    if (maxB < 1) maxB = 1;
    if (maxB > 4) maxB = 4;
    int grid = maxB * 256;

    void* args[] = {
        (void*)&X0, (void*)&Y0, (void*)&P,
        (void*)&X1, (void*)&Y1, (void*)&X2, (void*)&Y2, (void*)&X3, (void*)&Y3,
        (void*)&gw, (void*)&out
    };
    hipLaunchCooperativeKernel((void*)msssim_mega, dim3(grid), dim3(256), args, 0, stream);
}

// Round 8
// 240.918 us; speedup vs baseline: 2.9193x; 2.9193x over previous
//
#include <hip/hip_runtime.h>
#include <math.h>

#define HALO 10
#define TS 32
#define IN 42      // TS + HALO rows of blurred data per tile
#define HSTR 46    // LDS row stride (words) for Hs (transposed): 14*tx mod 32 period 16 -> 2-way only

typedef float f2 __attribute__((ext_vector_type(2)));

struct GaussW { float g[11]; };

// P2 level offsets (per-block partial slots): {0, 12288, 15360, 16128}, total 16320 floats
#define P2_TOTAL 16320

__global__ __launch_bounds__(256, 5) void ssim_level_kernel(
    const float* __restrict__ X, const float* __restrict__ Y,
    int H, GaussW gw, float* __restrict__ P2lvl, int last_level,
    float* __restrict__ Xpool, float* __restrict__ Ypool)
{
    const int W = H;
    const int Hout = H - HALO;

    __shared__ float Hs[4][TS][HSTR];   // [quantity][out_col][in_row], 23.5 KB
    __shared__ float red[4];

    const int tid = threadIdx.x;
    const int bc  = blockIdx.z;          // b*3 + c
    const int r0  = blockIdx.y * TS;
    const int c0  = blockIdx.x * TS;
    const size_t base = (size_t)bc * H * W;

    // ---- Phase A (waves 0-2): horizontal 11-tap blur of {x, y, (x+y)^2, (x-y)^2} ----
    // 42 rows x 4 segments of 8 output cols = 168 threads; inputs straight from global (L1/L2-hot).
    if (tid < 168) {
        const int rr  = tid >> 2;
        const int seg = tid & 3;
        const int ccb = seg * 8;
        const int gr  = r0 + rr;
        const int gc0 = c0 + ccb;
        const bool rowok = (gr < H);

        float x[20], y[20];
        if (rowok && (gc0 + 20 <= W)) {
            const float* xp = X + base + (size_t)gr * W + gc0;
            const float* yp = Y + base + (size_t)gr * W + gc0;
            #pragma unroll
            for (int v = 0; v < 5; ++v) {
                float4 xv = *(const float4*)(xp + 4 * v);
                float4 yv = *(const float4*)(yp + 4 * v);
                x[4*v+0] = xv.x; x[4*v+1] = xv.y; x[4*v+2] = xv.z; x[4*v+3] = xv.w;
                y[4*v+0] = yv.x; y[4*v+1] = yv.y; y[4*v+2] = yv.z; y[4*v+3] = yv.w;
            }
        } else {
            const int grc = rowok ? gr : (H - 1);
            const float* xp = X + base + (size_t)grc * W;
            const float* yp = Y + base + (size_t)grc * W;
            #pragma unroll
            for (int i = 0; i < 20; ++i) {
                int gc  = gc0 + i;
                int gcc = gc < W ? gc : (W - 1);
                bool ok = rowok && (gc < W);
                float xv = xp[gcc], yv = yp[gcc];
                x[i] = ok ? xv : 0.f;
                y[i] = ok ? yv : 0.f;
            }
        }

        // packed (v_pk_fma_f32) horizontal blurs: two adjacent outputs per f2 accumulator
        #pragma unroll
        for (int p = 0; p < 4; ++p) {
            f2 ax = {0.f, 0.f}, ay = {0.f, 0.f};
            #pragma unroll
            for (int k = 0; k < 11; ++k) {
                f2 vx = { x[2 * p + k], x[2 * p + k + 1] };
                f2 vy = { y[2 * p + k], y[2 * p + k + 1] };
                ax += vx * gw.g[k];
                ay += vy * gw.g[k];
            }
            Hs[0][ccb + 2 * p    ][rr] = ax.x;
            Hs[0][ccb + 2 * p + 1][rr] = ax.y;
            Hs[1][ccb + 2 * p    ][rr] = ay.x;
            Hs[1][ccb + 2 * p + 1][rr] = ay.y;
        }
        #pragma unroll
        for (int i = 0; i < 9; ++i) {
            f2 xv = *(f2*)&x[2 * i];
            f2 yv = *(f2*)&y[2 * i];
            f2 a = xv + yv;
            f2 d = xv - yv;
            *(f2*)&x[2 * i] = a * a;
            *(f2*)&y[2 * i] = d * d;
        }
        #pragma unroll
        for (int p = 0; p < 4; ++p) {
            f2 as = {0.f, 0.f}, ad = {0.f, 0.f};
            #pragma unroll
            for (int k = 0; k < 11; ++k) {
                f2 vs = { x[2 * p + k], x[2 * p + k + 1] };
                f2 vd = { y[2 * p + k], y[2 * p + k + 1] };
                as += vs * gw.g[k];
                ad += vd * gw.g[k];
            }
            Hs[2][ccb + 2 * p    ][rr] = as.x;
            Hs[2][ccb + 2 * p + 1][rr] = as.y;
            Hs[3][ccb + 2 * p    ][rr] = ad.x;
            Hs[3][ccb + 2 * p + 1][rr] = ad.y;
        }
    } else if (tid >= 192 && !last_level) {
        // ---- Phase A (wave 3): 2x2 avg-pool straight from global (tile is interior) ----
        const int t = tid - 192;
        const int Wp = W >> 1;
        #pragma unroll
        for (int q = 0; q < 4; ++q) {
            int cell = q * 64 + t;           // 0..255 -> 16x16 pool cells
            int pr = cell >> 4, pc = cell & 15;
            const size_t srow = base + (size_t)(r0 + 2 * pr) * W + (c0 + 2 * pc);
            float2 xa = *(const float2*)(X + srow);
            float2 xb = *(const float2*)(X + srow + W);
            float2 ya = *(const float2*)(Y + srow);
            float2 yb = *(const float2*)(Y + srow + W);
            size_t o = (size_t)bc * (H >> 1) * Wp + (size_t)(r0 / 2 + pr) * Wp + (c0 / 2 + pc);
            Xpool[o] = 0.25f * (xa.x + xa.y + xb.x + xb.y);
            Ypool[o] = 0.25f * (ya.x + ya.y + yb.x + yb.y);
        }
    }
    __syncthreads();

    // ---- Phase C (128 threads): vertical 11-tap blur, 8 outputs/thread + SSIM ----
    float acc_s = 0.f;
    if (tid < 128) {
        const int tx = tid & 31;     // output col
        const int tg = tid >> 5;     // 0..3, owns 8 consecutive output rows
        const int rb = tg * 8;

        f2 m1[4], m2[4], S[4], D[4];
        #define VPASS(Q, OUT)                                                    \
        {                                                                        \
            float win[18];                                                       \
            _Pragma("unroll")                                                    \
            for (int i = 0; i < 9; ++i)                                          \
                *(f2*)&win[2 * i] = *(const f2*)&Hs[Q][tx][rb + 2 * i];          \
            _Pragma("unroll")                                                    \
            for (int h = 0; h < 4; ++h) {                                        \
                f2 a = {0.f, 0.f};                                               \
                _Pragma("unroll")                                                \
                for (int k = 0; k < 11; ++k) {                                   \
                    f2 v = { win[2 * h + k], win[2 * h + k + 1] };               \
                    a += v * gw.g[k];                                            \
                }                                                                \
                OUT[h] = a;                                                      \
            }                                                                    \
        }
        VPASS(0, m1) VPASS(1, m2) VPASS(2, S) VPASS(3, D)
        #undef VPASS

        const float C1 = 1e-4f, C2 = 9e-4f;
        #pragma unroll
        for (int o = 0; o < 8; ++o) {
            float u1 = m1[o >> 1][o & 1], u2 = m2[o >> 1][o & 1];
            float Sv = S[o >> 1][o & 1],  Dv = D[o >> 1][o & 1];
            float u1s = u1 * u1, u2s = u2 * u2, u12 = u1 * u2;
            float ssum = 0.5f  * (Sv + Dv);     // blur(xx)+blur(yy)
            float sxy  = 0.25f * (Sv - Dv);     // blur(xy)
            float vsum = ssum - u1s - u2s;      // v1+v2
            float v12  = sxy - u12;
            float A2   = fmaxf(2.f * v12 + C2, 0.f);
            float B1   = u1s + u2s + C1;
            float B2   = vsum + C2;
            float inv  = __builtin_amdgcn_rcpf(B1 * B2);
            float val;
            if (!last_level) {             // levels 0-2: cs = A2/B2
                val = A2 * B1 * inv;
            } else {                       // level 3: ss = A1*A2/(B1*B2)
                float A1 = 2.f * u12 + C1;
                val = A1 * A2 * inv;
            }
            bool valid = (r0 + rb + o < Hout) && (c0 + tx < Hout);
            acc_s += valid ? val : 0.f;
        }
    }

    // ---- Phase D: block reduction + one plain store to a private slot ----
    #pragma unroll
    for (int off = 32; off; off >>= 1) acc_s += __shfl_down(acc_s, off);
    if ((tid & 63) == 0) red[tid >> 6] = acc_s;
    __syncthreads();
    if (tid == 0) {
        int lin = blockIdx.x + gridDim.x * (blockIdx.y + gridDim.y * blockIdx.z);
        P2lvl[lin] = red[0] + red[1];   // waves 2,3 contribute 0
    }
}

__global__ void finalize_kernel(const float* __restrict__ P2, float* __restrict__ out) {
    __shared__ float red[64][4];
    const int tid  = threadIdx.x;      // 256
    const int pair = tid >> 2;         // 0..63 = l*16 + b
    const int chnk = tid & 3;
    const int l = pair >> 4, b = pair & 15;
    const int off[4]  = {0, 12288, 15360, 16128};
    const int nper[4] = {768, 192, 48, 12};       // slots per batch (3 channels x tiles)
    const int n4 = nper[l] >> 2;
    const float* p = P2 + off[l] + b * nper[l] + chnk * n4;
    float s = 0.f;
    for (int j = 0; j < n4; ++j) s += p[j];
    red[pair][chnk] = s;
    __syncthreads();
    if (tid < 16) {
        const int bb = tid;
        const float wraw[4] = {0.0448f, 0.2856f, 0.3001f, 0.2363f};
        float wsum = wraw[0] + wraw[1] + wraw[2] + wraw[3];
        float ms = 1.f;
        for (int ll = 0; ll < 4; ++ll) {
            int Hh = 512 >> ll;
            int Ho = Hh - HALO;
            float cnt = 3.f * (float)Ho * (float)Ho;
            float val = (red[ll * 16 + bb][0] + red[ll * 16 + bb][1] +
                         red[ll * 16 + bb][2] + red[ll * 16 + bb][3]) / cnt;
            val = fmaxf(val, 1e-8f);
            ms *= powf(val, wraw[ll] / wsum);
        }
        out[bb] = 1.f - ms;
    }
}

extern "C" void kernel_launch(void* const* d_in, const int* in_sizes, int n_in,
                              void* d_out, int out_size, void* d_ws, size_t ws_size,
                              hipStream_t stream)
{
    const float* X0 = (const float*)d_in[0];
    const float* Y0 = (const float*)d_in[1];
    float* out = (float*)d_out;
    float* ws  = (float*)d_ws;

    // ws layout (floats): P2[16320] | X1 | Y1 | X2 | Y2 | X3 | Y3
    float* P2 = ws;
    float* X1 = ws + P2_TOTAL;
    float* Y1 = X1 + (size_t)16 * 3 * 256 * 256;
    float* X2 = Y1 + (size_t)16 * 3 * 256 * 256;
    float* Y2 = X2 + (size_t)16 * 3 * 128 * 128;
    float* X3 = Y2 + (size_t)16 * 3 * 128 * 128;
    float* Y3 = X3 + (size_t)16 * 3 * 64 * 64;

    GaussW gw;
    {
        float s = 0.f;
        for (int i = 0; i < 11; ++i) {
            float d = (float)(i - 5);
            gw.g[i] = expf(-d * d / (2.f * 1.5f * 1.5f));
            s += gw.g[i];
        }
        for (int i = 0; i < 11; ++i) gw.g[i] /= s;
    }

    hipLaunchKernelGGL(ssim_level_kernel, dim3(16, 16, 48), dim3(256), 0, stream,
                       X0, Y0, 512, gw, P2 + 0,     0, X1, Y1);
    hipLaunchKernelGGL(ssim_level_kernel, dim3(8, 8, 48),   dim3(256), 0, stream,
                       X1, Y1, 256, gw, P2 + 12288, 0, X2, Y2);
    hipLaunchKernelGGL(ssim_level_kernel, dim3(4, 4, 48),   dim3(256), 0, stream,
                       X2, Y2, 128, gw, P2 + 15360, 0, X3, Y3);
    hipLaunchKernelGGL(ssim_level_kernel, dim3(2, 2, 48),   dim3(256), 0, stream,
                       X3, Y3, 64,  gw, P2 + 16128, 1, (float*)nullptr, (float*)nullptr);

    hipLaunchKernelGGL(finalize_kernel, dim3(1), dim3(256), 0, stream, P2, out);
}

// Round 9
// 219.672 us; speedup vs baseline: 3.2016x; 1.0967x over previous
//
#include <hip/hip_runtime.h>
#include <math.h>

#define HALO 10
#define TS 32
#define INR 42        // staged rows per tile (TS + HALO)
#define STR 46        // LDS row stride (words): 2-way bank aliasing only (free), b64-aligned
#define P2_TOTAL 16320

typedef float f2 __attribute__((ext_vector_type(2)));

struct GaussW { float g[11]; };

// ---------------- pool kernel: X1/X2/X3 = 2x/4x/8x box means of X0 (hierarchical, exact) ----
__global__ void pool_all_kernel(
    const float* __restrict__ X0, const float* __restrict__ Y0,
    float* __restrict__ X1, float* __restrict__ Y1,
    float* __restrict__ X2, float* __restrict__ Y2,
    float* __restrict__ X3, float* __restrict__ Y3)
{
    const int gid = blockIdx.x * 256 + threadIdx.x;   // 196608 threads
    const int bc  = gid >> 12;                        // 48 channels
    const int rem = gid & 4095;
    const int R = rem >> 6, C = rem & 63;             // 8x8 input region (8R.., 8C..)

    const float* xin = X0 + (size_t)bc * 512 * 512;
    const float* yin = Y0 + (size_t)bc * 512 * 512;
    float* x1 = X1 + (size_t)bc * 256 * 256;
    float* y1 = Y1 + (size_t)bc * 256 * 256;
    float* x2 = X2 + (size_t)bc * 128 * 128;
    float* y2 = Y2 + (size_t)bc * 128 * 128;
    float* x3 = X3 + (size_t)bc * 64 * 64;
    float* y3 = Y3 + (size_t)bc * 64 * 64;

    float tx2a = 0.f, tx2b = 0.f, ty2a = 0.f, ty2b = 0.f, tx3 = 0.f, ty3 = 0.f;
    #pragma unroll
    for (int q = 0; q < 4; ++q) {                     // p1 rows
        const float* rx = xin + (size_t)(8 * R + 2 * q) * 512 + 8 * C;
        const float* ry = yin + (size_t)(8 * R + 2 * q) * 512 + 8 * C;
        float4 a0 = *(const float4*)rx,        b0 = *(const float4*)(rx + 4);
        float4 a1 = *(const float4*)(rx + 512), b1 = *(const float4*)(rx + 516);
        float4 c0v = *(const float4*)ry,        d0 = *(const float4*)(ry + 4);
        float4 c1v = *(const float4*)(ry + 512), d1 = *(const float4*)(ry + 516);
        float4 p1x, p1y;
        p1x.x = 0.25f * (a0.x + a0.y + a1.x + a1.y);
        p1x.y = 0.25f * (a0.z + a0.w + a1.z + a1.w);
        p1x.z = 0.25f * (b0.x + b0.y + b1.x + b1.y);
        p1x.w = 0.25f * (b0.z + b0.w + b1.z + b1.w);
        p1y.x = 0.25f * (c0v.x + c0v.y + c1v.x + c1v.y);
        p1y.y = 0.25f * (c0v.z + c0v.w + c1v.z + c1v.w);
        p1y.z = 0.25f * (d0.x + d0.y + d1.x + d1.y);
        p1y.w = 0.25f * (d0.z + d0.w + d1.z + d1.w);
        *(float4*)(x1 + (size_t)(4 * R + q) * 256 + 4 * C) = p1x;
        *(float4*)(y1 + (size_t)(4 * R + q) * 256 + 4 * C) = p1y;
        if ((q & 1) == 0) {
            tx2a = p1x.x + p1x.y; tx2b = p1x.z + p1x.w;
            ty2a = p1y.x + p1y.y; ty2b = p1y.z + p1y.w;
        } else {
            float2 p2x = { 0.25f * (tx2a + p1x.x + p1x.y), 0.25f * (tx2b + p1x.z + p1x.w) };
            float2 p2y = { 0.25f * (ty2a + p1y.x + p1y.y), 0.25f * (ty2b + p1y.z + p1y.w) };
            *(float2*)(x2 + (size_t)(2 * R + (q >> 1)) * 128 + 2 * C) = p2x;
            *(float2*)(y2 + (size_t)(2 * R + (q >> 1)) * 128 + 2 * C) = p2y;
            if (q == 1) { tx3 = p2x.x + p2x.y; ty3 = p2y.x + p2y.y; }
            else {
                x3[(size_t)R * 64 + C] = 0.25f * (tx3 + p2x.x + p2x.y);
                y3[(size_t)R * 64 + C] = 0.25f * (ty3 + p2y.x + p2y.y);
            }
        }
    }
}

// ---------------- unified SSIM kernel: all 4 levels in one dispatch ----------------
__global__ __launch_bounds__(256, 5) void ssim_all_kernel(
    const float* __restrict__ X0, const float* __restrict__ Y0,
    const float* __restrict__ X1, const float* __restrict__ Y1,
    const float* __restrict__ X2, const float* __restrict__ Y2,
    const float* __restrict__ X3, const float* __restrict__ Y3,
    GaussW gw, float* __restrict__ P2)
{
    // Union LDS: staging Xs[42][46] @0, Ys @1932; later Hs[4][32][46] @0 (23.0 KB)
    __shared__ float U[4 * TS * STR];
    __shared__ float red[2];

    const int tid = threadIdx.x;
    const int t   = blockIdx.x;

    int l, rem;
    if      (t < 12288) { l = 0; rem = t; }
    else if (t < 15360) { l = 1; rem = t - 12288; }
    else if (t < 16128) { l = 2; rem = t - 15360; }
    else                { l = 3; rem = t - 16128; }
    const int l2   = 4 - l;                 // log2(tiles per side)
    const int H    = 512 >> l;
    const int W    = H;
    const int Hout = H - HALO;
    const int bc   = rem >> (2 * l2);
    const int r2   = rem & ((1 << (2 * l2)) - 1);
    const int by   = r2 >> l2, bx = r2 & ((1 << l2) - 1);
    const int r0   = by * TS, c0 = bx * TS;
    const float* X = (l == 0) ? X0 : (l == 1) ? X1 : (l == 2) ? X2 : X3;
    const float* Y = (l == 0) ? Y0 : (l == 1) ? Y1 : (l == 2) ? Y2 : Y3;
    const size_t base = (size_t)bc * H * W;

    // ---- Phase 1: coalesced staging into union buffer ----
    for (int idx = tid; idx < INR * 22; idx += 256) {
        int rr = idx / 22, pp = idx - rr * 22;
        int gr = r0 + rr, gc = c0 + 2 * pp;
        float2 xv = make_float2(0.f, 0.f), yv = make_float2(0.f, 0.f);
        if (gr < H && gc < W) {
            xv = *(const float2*)(X + base + (size_t)gr * W + gc);
            yv = *(const float2*)(Y + base + (size_t)gr * W + gc);
        }
        *(float2*)&U[rr * STR + 2 * pp]              = xv;
        *(float2*)&U[INR * STR + rr * STR + 2 * pp]  = yv;
    }
    __syncthreads();

    // ---- Phase 2a: load private windows into registers (all staging reads) ----
    const int rr  = tid >> 2;
    const int seg = tid & 3;
    const int ccb = seg * 8;
    float x[20], y[20];
    if (tid < 168) {
        #pragma unroll
        for (int u = 0; u < 10; ++u) {
            *(f2*)&x[2 * u] = *(const f2*)&U[rr * STR + ccb + 2 * u];
            *(f2*)&y[2 * u] = *(const f2*)&U[INR * STR + rr * STR + ccb + 2 * u];
        }
    }
    __syncthreads();   // all reads of staging done; Hs may now overwrite it

    // ---- Phase 2b: horizontal 11-tap blur of {x, y, (x+y)^2, (x-y)^2} -> Hs (aliased) ----
    if (tid < 168) {
        #pragma unroll
        for (int p = 0; p < 4; ++p) {
            f2 ax = {0.f, 0.f}, ay = {0.f, 0.f};
            #pragma unroll
            for (int k = 0; k < 11; ++k) {
                f2 vx = { x[2 * p + k], x[2 * p + k + 1] };
                f2 vy = { y[2 * p + k], y[2 * p + k + 1] };
                ax += vx * gw.g[k];
                ay += vy * gw.g[k];
            }
            U[0 * TS * STR + (ccb + 2 * p) * STR + rr]     = ax.x;
            U[0 * TS * STR + (ccb + 2 * p + 1) * STR + rr] = ax.y;
            U[1 * TS * STR + (ccb + 2 * p) * STR + rr]     = ay.x;
            U[1 * TS * STR + (ccb + 2 * p + 1) * STR + rr] = ay.y;
        }
        #pragma unroll
        for (int i = 0; i < 9; ++i) {
            f2 xv = *(f2*)&x[2 * i];
            f2 yv = *(f2*)&y[2 * i];
            f2 a = xv + yv;
            f2 d = xv - yv;
            *(f2*)&x[2 * i] = a * a;
            *(f2*)&y[2 * i] = d * d;
        }
        #pragma unroll
        for (int p = 0; p < 4; ++p) {
            f2 as = {0.f, 0.f}, ad = {0.f, 0.f};
            #pragma unroll
            for (int k = 0; k < 11; ++k) {
                f2 vs = { x[2 * p + k], x[2 * p + k + 1] };
                f2 vd = { y[2 * p + k], y[2 * p + k + 1] };
                as += vs * gw.g[k];
                ad += vd * gw.g[k];
            }
            U[2 * TS * STR + (ccb + 2 * p) * STR + rr]     = as.x;
            U[2 * TS * STR + (ccb + 2 * p + 1) * STR + rr] = as.y;
            U[3 * TS * STR + (ccb + 2 * p) * STR + rr]     = ad.x;
            U[3 * TS * STR + (ccb + 2 * p + 1) * STR + rr] = ad.y;
        }
    }
    __syncthreads();

    // ---- Phase 3 (128 threads): vertical 11-tap blur, 8 outputs/thread + SSIM ----
    float acc_s = 0.f;
    if (tid < 128) {
        const int tx = tid & 31;          // output col
        const int tg = tid >> 5;          // 0..3 -> 8 consecutive output rows
        const int rb = tg * 8;

        f2 m1[4], m2[4], S[4], D[4];
        #define VPASS(Q, OUT)                                                    \
        {                                                                        \
            float win[18];                                                       \
            _Pragma("unroll")                                                    \
            for (int i = 0; i < 9; ++i)                                          \
                *(f2*)&win[2 * i] = *(const f2*)&U[(Q) * TS * STR + tx * STR + rb + 2 * i]; \
            _Pragma("unroll")                                                    \
            for (int h = 0; h < 4; ++h) {                                        \
                f2 a = {0.f, 0.f};                                               \
                _Pragma("unroll")                                                \
                for (int k = 0; k < 11; ++k) {                                   \
                    f2 v = { win[2 * h + k], win[2 * h + k + 1] };               \
                    a += v * gw.g[k];                                            \
                }                                                                \
                OUT[h] = a;                                                      \
            }                                                                    \
        }
        VPASS(0, m1) VPASS(1, m2) VPASS(2, S) VPASS(3, D)
        #undef VPASS

        const float C1 = 1e-4f, C2 = 9e-4f;
        #pragma unroll
        for (int o = 0; o < 8; ++o) {
            float u1 = m1[o >> 1][o & 1], u2 = m2[o >> 1][o & 1];
            float Sv = S[o >> 1][o & 1],  Dv = D[o >> 1][o & 1];
            float u1s = u1 * u1, u2s = u2 * u2, u12 = u1 * u2;
            float ssum = 0.5f  * (Sv + Dv);     // blur(xx)+blur(yy)
            float sxy  = 0.25f * (Sv - Dv);     // blur(xy)
            float vsum = ssum - u1s - u2s;      // v1+v2
            float v12  = sxy - u12;
            float A2   = fmaxf(2.f * v12 + C2, 0.f);
            float B1   = u1s + u2s + C1;
            float B2   = vsum + C2;
            float inv  = __builtin_amdgcn_rcpf(B1 * B2);
            float val;
            if (l != 3) {                  // levels 0-2: cs = A2/B2
                val = A2 * B1 * inv;
            } else {                       // level 3: ss = A1*A2/(B1*B2)
                float A1 = 2.f * u12 + C1;
                val = A1 * A2 * inv;
            }
            bool valid = (r0 + rb + o < Hout) && (c0 + tx < Hout);
            acc_s += valid ? val : 0.f;
        }
    }

    // ---- Phase 4: block reduction + one plain store to private slot ----
    #pragma unroll
    for (int off = 32; off; off >>= 1) acc_s += __shfl_down(acc_s, off);
    if (tid == 0)  red[0] = acc_s;
    if (tid == 64) red[1] = acc_s;
    __syncthreads();
    if (tid == 0) P2[t] = red[0] + red[1];
}

__global__ void finalize_kernel(const float* __restrict__ P2, float* __restrict__ out) {
    __shared__ float red[64][4];
    const int tid  = threadIdx.x;      // 256
    const int pair = tid >> 2;         // 0..63 = l*16 + b
    const int chnk = tid & 3;
    const int l = pair >> 4, b = pair & 15;
    const int off[4]  = {0, 12288, 15360, 16128};
    const int nper[4] = {768, 192, 48, 12};       // slots per batch
    const int n4 = nper[l] >> 2;
    const float* p = P2 + off[l] + b * nper[l] + chnk * n4;
    float s = 0.f;
    for (int j = 0; j < n4; ++j) s += p[j];
    red[pair][chnk] = s;
    __syncthreads();
    if (tid < 16) {
        const int bb = tid;
        const float wraw[4] = {0.0448f, 0.2856f, 0.3001f, 0.2363f};
        float wsum = wraw[0] + wraw[1] + wraw[2] + wraw[3];
        float ms = 1.f;
        for (int ll = 0; ll < 4; ++ll) {
            int Hh = 512 >> ll;
            int Ho = Hh - HALO;
            float cnt = 3.f * (float)Ho * (float)Ho;
            float val = (red[ll * 16 + bb][0] + red[ll * 16 + bb][1] +
                         red[ll * 16 + bb][2] + red[ll * 16 + bb][3]) / cnt;
            val = fmaxf(val, 1e-8f);
            ms *= powf(val, wraw[ll] / wsum);
        }
        out[bb] = 1.f - ms;
    }
}

extern "C" void kernel_launch(void* const* d_in, const int* in_sizes, int n_in,
                              void* d_out, int out_size, void* d_ws, size_t ws_size,
                              hipStream_t stream)
{
    const float* X0 = (const float*)d_in[0];
    const float* Y0 = (const float*)d_in[1];
    float* out = (float*)d_out;
    float* ws  = (float*)d_ws;

    // ws layout (floats): P2[16320] | X1 | Y1 | X2 | Y2 | X3 | Y3
    float* P2 = ws;
    float* X1 = ws + P2_TOTAL;
    float* Y1 = X1 + (size_t)16 * 3 * 256 * 256;
    float* X2 = Y1 + (size_t)16 * 3 * 256 * 256;
    float* Y2 = X2 + (size_t)16 * 3 * 128 * 128;
    float* X3 = Y2 + (size_t)16 * 3 * 128 * 128;
    float* Y3 = X3 + (size_t)16 * 3 * 64 * 64;

    GaussW gw;
    {
        float s = 0.f;
        for (int i = 0; i < 11; ++i) {
            float d = (float)(i - 5);
            gw.g[i] = expf(-d * d / (2.f * 1.5f * 1.5f));
            s += gw.g[i];
        }
        for (int i = 0; i < 11; ++i) gw.g[i] /= s;
    }

    hipLaunchKernelGGL(pool_all_kernel, dim3(768), dim3(256), 0, stream,
                       X0, Y0, X1, Y1, X2, Y2, X3, Y3);
    hipLaunchKernelGGL(ssim_all_kernel, dim3(16320), dim3(256), 0, stream,
                       X0, Y0, X1, Y1, X2, Y2, X3, Y3, gw, P2);
    hipLaunchKernelGGL(finalize_kernel, dim3(1), dim3(256), 0, stream, P2, out);
}

// Round 10
// 211.407 us; speedup vs baseline: 3.3268x; 1.0391x over previous
//
#include <hip/hip_runtime.h>
#include <math.h>

#define HALO 10
#define TS 32
#define INR 42        // staged rows per tile (TS + HALO)
#define STR 46        // LDS row stride (words): 2-way bank aliasing only (free), b64-aligned
#define P2_TOTAL 16320

typedef float f2 __attribute__((ext_vector_type(2)));

struct GaussW { float g[11]; };

// ---------------- unified SSIM kernel ----------------
// Dispatch A: tbase=0,     12288 blocks (level 0) + fused hierarchical pooling -> X1/X2/X3
// Dispatch B: tbase=12288,  4032 blocks (levels 1-3), reads pooled pyramids
__global__ __launch_bounds__(256, 6) void ssim_kernel(
    const float* __restrict__ X0, const float* __restrict__ Y0,
    float* __restrict__ X1, float* __restrict__ Y1,
    float* __restrict__ X2, float* __restrict__ Y2,
    float* __restrict__ X3, float* __restrict__ Y3,
    GaussW gw, float* __restrict__ P2, int tbase)
{
    // Union LDS: staging Xs[42][46] @0, Ys @ INR*STR; later Hs[4][32][46] @0 (23.0 KB)
    __shared__ float U[4 * TS * STR];
    __shared__ float red[2];

    const int tid = threadIdx.x;
    const int t   = blockIdx.x + tbase;

    int l, rem;
    if      (t < 12288) { l = 0; rem = t; }
    else if (t < 15360) { l = 1; rem = t - 12288; }
    else if (t < 16128) { l = 2; rem = t - 15360; }
    else                { l = 3; rem = t - 16128; }
    const int l2   = 4 - l;                 // log2(tiles per side)
    const int H    = 512 >> l;
    const int W    = H;
    const int Hout = H - HALO;
    const int bc   = rem >> (2 * l2);
    const int r2   = rem & ((1 << (2 * l2)) - 1);
    const int by   = r2 >> l2, bx = r2 & ((1 << l2) - 1);
    const int r0   = by * TS, c0 = bx * TS;
    const float* X = (l == 0) ? X0 : (l == 1) ? X1 : (l == 2) ? X2 : X3;
    const float* Y = (l == 0) ? Y0 : (l == 1) ? Y1 : (l == 2) ? Y2 : Y3;
    const size_t base = (size_t)bc * H * W;

    // ---- Phase 1: coalesced staging into union buffer ----
    for (int idx = tid; idx < INR * 22; idx += 256) {
        int rr = idx / 22, pp = idx - rr * 22;
        int gr = r0 + rr, gc = c0 + 2 * pp;
        float2 xv = make_float2(0.f, 0.f), yv = make_float2(0.f, 0.f);
        if (gr < H && gc < W) {
            xv = *(const float2*)(X + base + (size_t)gr * W + gc);
            yv = *(const float2*)(Y + base + (size_t)gr * W + gc);
        }
        *(float2*)&U[rr * STR + 2 * pp]              = xv;
        *(float2*)&U[INR * STR + rr * STR + 2 * pp]  = yv;
    }
    __syncthreads();

    // ---- Phase 2a: all reads of the staging region (windows + pool cells) ----
    const int rr  = tid >> 2;
    const int seg = tid & 3;
    const int ccb = seg * 8;
    float x[20], y[20];
    if (tid < 168) {
        #pragma unroll
        for (int u = 0; u < 10; ++u) {
            *(f2*)&x[2 * u] = *(const f2*)&U[rr * STR + ccb + 2 * u];
            *(f2*)&y[2 * u] = *(const f2*)&U[INR * STR + rr * STR + ccb + 2 * u];
        }
    }
    float p1x = 0.f, p1y = 0.f;
    if (l == 0) {
        // each thread owns one 2x2 pool cell (pr,pc) of this tile's 32x32 body
        const int pr = tid >> 4, pc = tid & 15;
        f2 xa = *(const f2*)&U[(2 * pr) * STR + 2 * pc];
        f2 xb = *(const f2*)&U[(2 * pr + 1) * STR + 2 * pc];
        f2 ya = *(const f2*)&U[INR * STR + (2 * pr) * STR + 2 * pc];
        f2 yb = *(const f2*)&U[INR * STR + (2 * pr + 1) * STR + 2 * pc];
        p1x = 0.25f * (xa.x + xa.y + xb.x + xb.y);
        p1y = 0.25f * (ya.x + ya.y + yb.x + yb.y);
    }
    __syncthreads();   // staging reads done; Hs may overwrite

    // ---- Phase 2b: horizontal 11-tap blur of {x, y, (x+y)^2, (x-y)^2} -> Hs (aliased) ----
    if (tid < 168) {
        #pragma unroll
        for (int p = 0; p < 4; ++p) {
            f2 ax = {0.f, 0.f}, ay = {0.f, 0.f};
            #pragma unroll
            for (int k = 0; k < 11; ++k) {
                f2 vx = { x[2 * p + k], x[2 * p + k + 1] };
                f2 vy = { y[2 * p + k], y[2 * p + k + 1] };
                ax += vx * gw.g[k];
                ay += vy * gw.g[k];
            }
            U[0 * TS * STR + (ccb + 2 * p) * STR + rr]     = ax.x;
            U[0 * TS * STR + (ccb + 2 * p + 1) * STR + rr] = ax.y;
            U[1 * TS * STR + (ccb + 2 * p) * STR + rr]     = ay.x;
            U[1 * TS * STR + (ccb + 2 * p + 1) * STR + rr] = ay.y;
        }
        #pragma unroll
        for (int i = 0; i < 9; ++i) {
            f2 xv = *(f2*)&x[2 * i];
            f2 yv = *(f2*)&y[2 * i];
            f2 a = xv + yv;
            f2 d = xv - yv;
            *(f2*)&x[2 * i] = a * a;
            *(f2*)&y[2 * i] = d * d;
        }
        #pragma unroll
        for (int p = 0; p < 4; ++p) {
            f2 as = {0.f, 0.f}, ad = {0.f, 0.f};
            #pragma unroll
            for (int k = 0; k < 11; ++k) {
                f2 vs = { x[2 * p + k], x[2 * p + k + 1] };
                f2 vd = { y[2 * p + k], y[2 * p + k + 1] };
                as += vs * gw.g[k];
                ad += vd * gw.g[k];
            }
            U[2 * TS * STR + (ccb + 2 * p) * STR + rr]     = as.x;
            U[2 * TS * STR + (ccb + 2 * p + 1) * STR + rr] = as.y;
            U[3 * TS * STR + (ccb + 2 * p) * STR + rr]     = ad.x;
            U[3 * TS * STR + (ccb + 2 * p + 1) * STR + rr] = ad.y;
        }
    }

    // ---- Pool outputs (level 0 only): X1 direct; X2/X3 via shfl_xor trees ----
    if (l == 0) {
        const int pr = tid >> 4, pc = tid & 15;
        size_t o1 = (size_t)bc * 256 * 256 + (size_t)(r0 / 2 + pr) * 256 + (c0 / 2 + pc);
        X1[o1] = p1x;
        Y1[o1] = p1y;
        float sx = p1x + __shfl_xor(p1x, 1);  sx += __shfl_xor(sx, 16);
        float sy = p1y + __shfl_xor(p1y, 1);  sy += __shfl_xor(sy, 16);
        float p2x = 0.25f * sx, p2y = 0.25f * sy;
        if ((tid & 17) == 0) {          // pr, pc even
            size_t o2 = (size_t)bc * 128 * 128 + (size_t)(r0 / 4 + (pr >> 1)) * 128 + (c0 / 4 + (pc >> 1));
            X2[o2] = p2x;
            Y2[o2] = p2y;
        }
        float tx3 = p2x + __shfl_xor(p2x, 2);  tx3 += __shfl_xor(tx3, 32);
        float ty3 = p2y + __shfl_xor(p2y, 2);  ty3 += __shfl_xor(ty3, 32);
        if ((tid & 51) == 0) {          // pr, pc multiples of 4
            size_t o3 = (size_t)bc * 64 * 64 + (size_t)(r0 / 8 + (pr >> 2)) * 64 + (c0 / 8 + (pc >> 2));
            X3[o3] = 0.25f * tx3;
            Y3[o3] = 0.25f * ty3;
        }
    }
    __syncthreads();

    // ---- Phase 3 (128 threads): vertical 11-tap blur, 8 outputs/thread + SSIM ----
    float acc_s = 0.f;
    if (tid < 128) {
        const int tx = tid & 31;          // output col
        const int tg = tid >> 5;          // 0..3 -> 8 consecutive output rows
        const int rb = tg * 8;

        f2 m1[4], m2[4], S[4], D[4];
        #define VPASS(Q, OUT)                                                    \
        {                                                                        \
            float win[18];                                                       \
            _Pragma("unroll")                                                    \
            for (int i = 0; i < 9; ++i)                                          \
                *(f2*)&win[2 * i] = *(const f2*)&U[(Q) * TS * STR + tx * STR + rb + 2 * i]; \
            _Pragma("unroll")                                                    \
            for (int h = 0; h < 4; ++h) {                                        \
                f2 a = {0.f, 0.f};                                               \
                _Pragma("unroll")                                                \
                for (int k = 0; k < 11; ++k) {                                   \
                    f2 v = { win[2 * h + k], win[2 * h + k + 1] };               \
                    a += v * gw.g[k];                                            \
                }                                                                \
                OUT[h] = a;                                                      \
            }                                                                    \
        }
        VPASS(0, m1) VPASS(1, m2) VPASS(2, S) VPASS(3, D)
        #undef VPASS

        const float C1 = 1e-4f, C2 = 9e-4f;
        #pragma unroll
        for (int o = 0; o < 8; ++o) {
            float u1 = m1[o >> 1][o & 1], u2 = m2[o >> 1][o & 1];
            float Sv = S[o >> 1][o & 1],  Dv = D[o >> 1][o & 1];
            float u1s = u1 * u1, u2s = u2 * u2, u12 = u1 * u2;
            float ssum = 0.5f  * (Sv + Dv);     // blur(xx)+blur(yy)
            float sxy  = 0.25f * (Sv - Dv);     // blur(xy)
            float vsum = ssum - u1s - u2s;      // v1+v2
            float v12  = sxy - u12;
            float A2   = fmaxf(2.f * v12 + C2, 0.f);
            float B1   = u1s + u2s + C1;
            float B2   = vsum + C2;
            float inv  = __builtin_amdgcn_rcpf(B1 * B2);
            float val;
            if (l != 3) {                  // levels 0-2: cs = A2/B2
                val = A2 * B1 * inv;
            } else {                       // level 3: ss = A1*A2/(B1*B2)
                float A1 = 2.f * u12 + C1;
                val = A1 * A2 * inv;
            }
            bool valid = (r0 + rb + o < Hout) && (c0 + tx < Hout);
            acc_s += valid ? val : 0.f;
        }
    }

    // ---- Phase 4: block reduction + one plain store to private slot ----
    #pragma unroll
    for (int off = 32; off; off >>= 1) acc_s += __shfl_down(acc_s, off);
    if (tid == 0)  red[0] = acc_s;
    if (tid == 64) red[1] = acc_s;
    __syncthreads();
    if (tid == 0) P2[t] = red[0] + red[1];
}

__global__ void finalize_kernel(const float* __restrict__ P2, float* __restrict__ out) {
    __shared__ float red[64][4];
    const int tid  = threadIdx.x;      // 256
    const int pair = tid >> 2;         // 0..63 = l*16 + b
    const int chnk = tid & 3;
    const int l = pair >> 4, b = pair & 15;
    const int off[4]  = {0, 12288, 15360, 16128};
    const int nper[4] = {768, 192, 48, 12};       // slots per batch
    const int n4 = nper[l] >> 2;
    const float* p = P2 + off[l] + b * nper[l] + chnk * n4;
    float s = 0.f;
    for (int j = 0; j < n4; ++j) s += p[j];
    red[pair][chnk] = s;
    __syncthreads();
    if (tid < 16) {
        const int bb = tid;
        const float wraw[4] = {0.0448f, 0.2856f, 0.3001f, 0.2363f};
        float wsum = wraw[0] + wraw[1] + wraw[2] + wraw[3];
        float ms = 1.f;
        for (int ll = 0; ll < 4; ++ll) {
            int Hh = 512 >> ll;
            int Ho = Hh - HALO;
            float cnt = 3.f * (float)Ho * (float)Ho;
            float val = (red[ll * 16 + bb][0] + red[ll * 16 + bb][1] +
                         red[ll * 16 + bb][2] + red[ll * 16 + bb][3]) / cnt;
            val = fmaxf(val, 1e-8f);
            ms *= powf(val, wraw[ll] / wsum);
        }
        out[bb] = 1.f - ms;
    }
}

extern "C" void kernel_launch(void* const* d_in, const int* in_sizes, int n_in,
                              void* d_out, int out_size, void* d_ws, size_t ws_size,
                              hipStream_t stream)
{
    const float* X0 = (const float*)d_in[0];
    const float* Y0 = (const float*)d_in[1];
    float* out = (float*)d_out;
    float* ws  = (float*)d_ws;

    // ws layout (floats): P2[16320] | X1 | Y1 | X2 | Y2 | X3 | Y3
    float* P2 = ws;
    float* X1 = ws + P2_TOTAL;
    float* Y1 = X1 + (size_t)16 * 3 * 256 * 256;
    float* X2 = Y1 + (size_t)16 * 3 * 256 * 256;
    float* Y2 = X2 + (size_t)16 * 3 * 128 * 128;
    float* X3 = Y2 + (size_t)16 * 3 * 128 * 128;
    float* Y3 = X3 + (size_t)16 * 3 * 64 * 64;

    GaussW gw;
    {
        float s = 0.f;
        for (int i = 0; i < 11; ++i) {
            float d = (float)(i - 5);
            gw.g[i] = expf(-d * d / (2.f * 1.5f * 1.5f));
            s += gw.g[i];
        }
        for (int i = 0; i < 11; ++i) gw.g[i] /= s;
    }

    // Dispatch A: level 0 + fused pyramid pooling
    hipLaunchKernelGGL(ssim_kernel, dim3(12288), dim3(256), 0, stream,
                       X0, Y0, X1, Y1, X2, Y2, X3, Y3, gw, P2, 0);
    // Dispatch B: levels 1-3
    hipLaunchKernelGGL(ssim_kernel, dim3(4032), dim3(256), 0, stream,
                       X0, Y0, X1, Y1, X2, Y2, X3, Y3, gw, P2, 12288);
    hipLaunchKernelGGL(finalize_kernel, dim3(1), dim3(256), 0, stream, P2, out);
}